// Round 1
// baseline (367.847 us; speedup 1.0000x reference)
//
#include <hip/hip_runtime.h>
#include <hip/hip_bf16.h>

// Problem constants (from reference)
#define B_DIM  8192
#define N_  32
#define ND_ 16
#define ED_ 8
#define GD_ 8
#define HN_ 128
#define HE_ 128
#define HG_ 128
#define HC_ 64

// 4x4 register-tile FMA over 4 consecutive k's.
// in_rows[r]: pointer to LDS row for tile-row r. W row-major [K][128].
__device__ __forceinline__ void tile_fma_4x4(
    float acc[4][4], const float* in0, const float* in1, const float* in2,
    const float* in3, int k, const float* __restrict__ W, int wrow, int c4)
{
    float in_[4][4];
    *(float4*)&in_[0][0] = *(const float4*)(in0 + k);
    *(float4*)&in_[1][0] = *(const float4*)(in1 + k);
    *(float4*)&in_[2][0] = *(const float4*)(in2 + k);
    *(float4*)&in_[3][0] = *(const float4*)(in3 + k);
#pragma unroll
    for (int kk = 0; kk < 4; ++kk) {
        float w_[4];
        *(float4*)w_ = *(const float4*)&W[(wrow + kk) * 128 + c4];
#pragma unroll
        for (int r = 0; r < 4; ++r) {
#pragma unroll
            for (int c = 0; c < 4; ++c)
                acc[r][c] += in_[r][kk] * w_[c];
        }
    }
}

__global__ __launch_bounds__(256, 3) void gnn_fused(
    const float* __restrict__ gf,   // [B,8]
    const float* __restrict__ nf,   // [B,32,16]
    const float* __restrict__ ef,   // [B,31,8]
    const void*  __restrict__ nmask_raw, // [B,32] bool (u8 or i32 — detected)
    const float* __restrict__ Wn, const float* __restrict__ bn,   // [40,128],[128]
    const float* __restrict__ We, const float* __restrict__ be,   // [272,128],[128]
    const float* __restrict__ Ws, const float* __restrict__ bs,   // [128,1],[1]
    const float* __restrict__ Wg, const float* __restrict__ bg,   // [128,128],[128]
    const float* __restrict__ Wc1, const float* __restrict__ bc1, // [128,64],[64]
    const float* __restrict__ Wc2, const float* __restrict__ bc2, // [64,1],[1]
    float* __restrict__ out)        // [B]
{
    const int b = blockIdx.x;
    const int t = threadIdx.x;

    __shared__ __align__(16) float s_g[GD_];
    __shared__ int   s_mi[N_];
    __shared__ float s_emask[N_];
    __shared__ __align__(16) float s_ef[N_][ED_];    // raw edge feats, row 31 = 0
    __shared__ __align__(16) float s_efm[N_][ED_];   // masked edge feats, row 31 = 0
    __shared__ __align__(16) float s_nin[N_][32];    // node MLP input (g folded into bias)
    __shared__ __align__(16) float s_hn[N_ + 1][HN_]; // h_node, row 32 = 0
    __shared__ __align__(16) float s_he[N_][HE_];    // h_edge, row 31 dummy
    __shared__ __align__(16) float s_bias1[HN_];     // bn + g@Wn[32:40]
    __shared__ __align__(16) float s_bias2[HE_];     // be + g@We[264:272]
    __shared__ float s_sc[N_];                       // raw scores
    __shared__ float s_w[N_];                        // softmax weights, [31]=0
    __shared__ __align__(16) float s_tmp[256];
    __shared__ __align__(16) float s_aggf[HE_];
    __shared__ __align__(16) float s_hg[HG_];
    __shared__ __align__(16) float s_hc[HC_];

    // ---- node_mask dtype detection (bool-as-u8 vs int32), deterministic ----
    const unsigned char* mb = (const unsigned char*)nmask_raw;
    int cnt = __syncthreads_count(mb[t] != 0);  // first 256 bytes
    const bool is_u8 = (cnt > 96);  // u8 random 0/1 => ~128; i32 0/1 => <=64

    // ---- P0: loads ----
    if (t < GD_) s_g[t] = gf[b * GD_ + t];
    for (int idx = t; idx < N_ * ND_; idx += 256)
        s_nin[idx >> 4][idx & 15] = nf[b * N_ * ND_ + idx];
    for (int idx = t; idx < (N_ - 1) * ED_; idx += 256)
        s_ef[idx >> 3][idx & 7] = ef[b * (N_ - 1) * ED_ + idx];
    if (t < ED_) s_ef[N_ - 1][t] = 0.0f;
    if (t < HN_) s_hn[N_][t] = 0.0f;
    if (t < N_) {
        int mv = is_u8 ? (int)mb[b * N_ + t] : ((const int*)nmask_raw)[b * N_ + t];
        s_mi[t] = mv;
    }
    __syncthreads();

    if (t < N_)
        s_emask[t] = (t < N_ - 1 && s_mi[t] != 0 && s_mi[t + 1] != 0) ? 1.0f : 0.0f;
    __syncthreads();

    {   // masked edge features
        int e = t >> 3, k = t & 7;
        s_efm[e][k] = s_ef[e][k] * s_emask[e];
    }
    {   // combined biases (fold g@W tail rows)
        int j = t & 127;
        if (t < 128) {
            float v = bn[j];
#pragma unroll
            for (int k = 0; k < GD_; ++k)
                v += s_g[k] * Wn[(ND_ + 2 * ED_ + k) * HN_ + j];
            s_bias1[j] = v;
        } else {
            float v = be[j];
#pragma unroll
            for (int k = 0; k < GD_; ++k)
                v += s_g[k] * We[(ED_ + 2 * HN_ + k) * HE_ + j];
            s_bias2[j] = v;
        }
    }
    __syncthreads();

    // node input tail: k 16..23 = edge_backward, 24..31 = edge_forward
    for (int idx = t; idx < N_ * 16; idx += 256) {
        int n = idx >> 4, kk = idx & 15;
        if (kk < 8) s_nin[n][16 + kk]      = (n > 0)      ? s_efm[n - 1][kk]     : 0.0f;
        else        s_nin[n][24 + (kk - 8)] = (n < N_ - 1) ? s_efm[n][kk - 8]     : 0.0f;
    }
    __syncthreads();

    const int jg = t & 31, rg = t >> 5;
    const int c4 = jg * 4, r4 = rg * 4;

    // ---- P1: node MLP  h_node = relu(nin @ Wn[0:32] + bias1) ----
    {
        float acc[4][4];
#pragma unroll
        for (int r = 0; r < 4; ++r)
#pragma unroll
            for (int c = 0; c < 4; ++c) acc[r][c] = s_bias1[c4 + c];
        const float* i0 = &s_nin[r4 + 0][0];
        const float* i1 = &s_nin[r4 + 1][0];
        const float* i2 = &s_nin[r4 + 2][0];
        const float* i3 = &s_nin[r4 + 3][0];
#pragma unroll
        for (int k = 0; k < 32; k += 4)
            tile_fma_4x4(acc, i0, i1, i2, i3, k, Wn, k, c4);
#pragma unroll
        for (int r = 0; r < 4; ++r)
#pragma unroll
            for (int c = 0; c < 4; ++c)
                s_hn[r4 + r][c4 + c] = fmaxf(acc[r][c], 0.0f);
    }
    __syncthreads();

    // ---- P2: edge MLP  h_edge = relu([ef, hn[e], hn[e+1]] @ We + bias2) ----
    {
        float acc[4][4];
#pragma unroll
        for (int r = 0; r < 4; ++r)
#pragma unroll
            for (int c = 0; c < 4; ++c) acc[r][c] = s_bias2[c4 + c];
        // segment A: raw edge features, We rows 0..7
        {
            const float* i0 = &s_ef[r4 + 0][0];
            const float* i1 = &s_ef[r4 + 1][0];
            const float* i2 = &s_ef[r4 + 2][0];
            const float* i3 = &s_ef[r4 + 3][0];
#pragma unroll
            for (int k = 0; k < 8; k += 4)
                tile_fma_4x4(acc, i0, i1, i2, i3, k, We, k, c4);
        }
        // segment B: h_node[e], We rows 8..135
        {
            const float* i0 = &s_hn[r4 + 0][0];
            const float* i1 = &s_hn[r4 + 1][0];
            const float* i2 = &s_hn[r4 + 2][0];
            const float* i3 = &s_hn[r4 + 3][0];
#pragma unroll 4
            for (int k = 0; k < 128; k += 4)
                tile_fma_4x4(acc, i0, i1, i2, i3, k, We, 8 + k, c4);
        }
        // segment C: h_node[e+1], We rows 136..263
        {
            const float* i0 = &s_hn[r4 + 1][0];
            const float* i1 = &s_hn[r4 + 2][0];
            const float* i2 = &s_hn[r4 + 3][0];
            const float* i3 = &s_hn[r4 + 4][0];
#pragma unroll 4
            for (int k = 0; k < 128; k += 4)
                tile_fma_4x4(acc, i0, i1, i2, i3, k, We, 136 + k, c4);
        }
#pragma unroll
        for (int r = 0; r < 4; ++r)
#pragma unroll
            for (int c = 0; c < 4; ++c)
                s_he[r4 + r][c4 + c] = fmaxf(acc[r][c], 0.0f);
    }
    __syncthreads();

    // ---- P3: scores + masked softmax ----
    {
        int c = t & 7, e = t >> 3;
        const float* he = &s_he[e][0];
        float p = 0.0f;
#pragma unroll
        for (int j0 = 0; j0 < 16; j0 += 4) {
            float4 h = *(const float4*)&he[c * 16 + j0];
            float4 w = *(const float4*)&Ws[c * 16 + j0];
            p += h.x * w.x + h.y * w.y + h.z * w.z + h.w * w.w;
        }
        p += __shfl_xor(p, 1);
        p += __shfl_xor(p, 2);
        p += __shfl_xor(p, 4);
        if (c == 0) s_sc[e] = p + bs[0];
    }
    __syncthreads();
    if (t < 64) {
        float v = -INFINITY;
        if (t < N_ - 1)
            v = s_sc[t] * s_emask[t] + (1.0f - s_emask[t]) * (-1e9f);
        float m = v;
#pragma unroll
        for (int d = 32; d >= 1; d >>= 1) m = fmaxf(m, __shfl_xor(m, d));
        float e_ = (t < N_ - 1) ? expf(v - m) : 0.0f;
        float ssum = e_;
#pragma unroll
        for (int d = 32; d >= 1; d >>= 1) ssum += __shfl_xor(ssum, d);
        if (t < N_) s_w[t] = (t < N_ - 1) ? (e_ / ssum) : 0.0f;
    }
    __syncthreads();

    // ---- P4: weighted edge pooling ----
    {
        int j = t & 127, half = t >> 7;
        float p = 0.0f;
#pragma unroll
        for (int e = 0; e < 16; ++e) {
            int ee = half * 16 + e;
            p += s_he[ee][j] * s_w[ee];
        }
        s_tmp[half * 128 + j] = p;
    }
    __syncthreads();
    if (t < 128) s_aggf[t] = s_tmp[t] + s_tmp[128 + t];
    __syncthreads();

    // ---- P5: h_glob = relu(agg @ Wg + bg) ----
    {
        int j = t & 127, half = t >> 7;
        float p = 0.0f;
        for (int k = half * 64; k < half * 64 + 64; ++k)
            p += s_aggf[k] * Wg[k * HG_ + j];
        s_tmp[half * 128 + j] = p;
    }
    __syncthreads();
    if (t < 128) s_hg[t] = fmaxf(s_tmp[t] + s_tmp[128 + t] + bg[t], 0.0f);
    __syncthreads();

    // ---- P6: h_cls = relu(h_glob @ Wc1 + bc1) ----
    {
        int j = t & 63, q = t >> 6;
        float p = 0.0f;
        for (int k = q * 32; k < q * 32 + 32; ++k)
            p += s_hg[k] * Wc1[k * HC_ + j];
        s_tmp[q * 64 + j] = p;
    }
    __syncthreads();
    if (t < 64)
        s_hc[t] = fmaxf(s_tmp[t] + s_tmp[64 + t] + s_tmp[128 + t] + s_tmp[192 + t] + bc1[t], 0.0f);
    __syncthreads();

    // ---- P7: y = h_cls @ Wc2 + bc2 ----
    if (t < 64) {
        float p = s_hc[t] * Wc2[t];
#pragma unroll
        for (int d = 32; d >= 1; d >>= 1) p += __shfl_xor(p, d);
        if (t == 0) out[b] = p + bc2[0];
    }
}

extern "C" void kernel_launch(void* const* d_in, const int* in_sizes, int n_in,
                              void* d_out, int out_size, void* d_ws, size_t ws_size,
                              hipStream_t stream) {
    const float* gf  = (const float*)d_in[0];
    const float* nf  = (const float*)d_in[1];
    const float* ef  = (const float*)d_in[2];
    const void*  nm  = d_in[3];
    const float* Wn  = (const float*)d_in[4];
    const float* bn  = (const float*)d_in[5];
    const float* We  = (const float*)d_in[6];
    const float* be  = (const float*)d_in[7];
    const float* Ws  = (const float*)d_in[8];
    const float* bs  = (const float*)d_in[9];
    const float* Wg  = (const float*)d_in[10];
    const float* bg  = (const float*)d_in[11];
    const float* Wc1 = (const float*)d_in[12];
    const float* bc1 = (const float*)d_in[13];
    const float* Wc2 = (const float*)d_in[14];
    const float* bc2 = (const float*)d_in[15];
    float* out = (float*)d_out;

    const int B = in_sizes[0] / GD_;   // 8192
    gnn_fused<<<B, 256, 0, stream>>>(gf, nf, ef, nm, Wn, bn, We, be, Ws, bs,
                                     Wg, bg, Wc1, bc1, Wc2, bc2, out);
}

// Round 2
// 127.888 us; speedup vs baseline: 2.8763x; 2.8763x over previous
//
#include <hip/hip_runtime.h>
#include <hip/hip_bf16.h>

// Problem constants (from reference)
#define N_  32
#define ND_ 16
#define ED_ 8
#define GD_ 8
#define HN_ 128
#define HE_ 128
#define HG_ 128
#define HC_ 64

typedef __attribute__((ext_vector_type(8))) short short8_t;
typedef __attribute__((ext_vector_type(4))) float f32x4;

#define MFMA16(a, b, c) __builtin_amdgcn_mfma_f32_16x16x32_bf16((a), (b), (c), 0, 0, 0)

__device__ __forceinline__ unsigned short f2bf(float f) {
    unsigned int u = __float_as_uint(f);
    unsigned int r = u + 0x7FFFu + ((u >> 16) & 1u);
    return (unsigned short)(r >> 16);
}
__device__ __forceinline__ float bf2f(unsigned short h) {
    return __uint_as_float(((unsigned int)h) << 16);
}

// ---- workspace layout (ushort elements) ----
// WnS: 1 K-step x 8 N-tiles x 64 lanes x 8 = 4096 each (hi, lo)
// WeS: 9 K-steps x 8 N-tiles x 64 lanes x 8 = 36864 each (hi, lo)
#define WNS_HI 0
#define WNS_LO 4096
#define WES_HI 8192
#define WES_LO (8192 + 36864)
#define WS_USHORTS (8192 + 2 * 36864)   // 81920 ushorts = 163840 bytes
#define WS_BYTES (WS_USHORTS * 2)

// Prologue: convert + swizzle weights into B-fragment-major bf16 hi/lo.
// Fragment layout (16x16x32 bf16): lane l holds B[k = 32*s + 8*(l>>4)+i][col = 16*n + (l&15)]
__global__ void prep_weights(const float* __restrict__ Wn,
                             const float* __restrict__ We,
                             unsigned short* __restrict__ wsp) {
    int gid = blockIdx.x * 256 + threadIdx.x;
    if (gid >= 512 + 4608) return;
    float vals[8];
    unsigned short* dh;
    unsigned short* dl;
    if (gid < 512) {
        int l = gid & 63, n = (gid >> 6) & 7;
        int c = 16 * n + (l & 15);
#pragma unroll
        for (int i = 0; i < 8; ++i) {
            int k = 8 * (l >> 4) + i;            // 0..31 (g folded into bias)
            vals[i] = Wn[k * HN_ + c];
        }
        dh = wsp + WNS_HI + gid * 8;
        dl = wsp + WNS_LO + gid * 8;
    } else {
        int g2 = gid - 512;
        int l = g2 & 63, n = (g2 >> 6) & 7, s = g2 >> 9;   // s in 0..8
        int c = 16 * n + (l & 15);
#pragma unroll
        for (int i = 0; i < 8; ++i) {
            int kl = 8 * (l >> 4) + i;           // 0..31 within K-step
            int ks;
            if (s == 0)      ks = (kl < 8) ? kl : -1;          // ef rows 0..7, pad zero
            else if (s <= 4) ks = 8 + (s - 1) * 32 + kl;       // h_node[e]   rows 8..135
            else             ks = 136 + (s - 5) * 32 + kl;     // h_node[e+1] rows 136..263
            vals[i] = (ks >= 0) ? We[ks * HE_ + c] : 0.0f;
        }
        dh = wsp + WES_HI + g2 * 8;
        dl = wsp + WES_LO + g2 * 8;
    }
    unsigned short h[8], lo[8];
#pragma unroll
    for (int i = 0; i < 8; ++i) {
        h[i] = f2bf(vals[i]);
        lo[i] = f2bf(vals[i] - bf2f(h[i]));
    }
    *(short8_t*)dh = *(short8_t*)h;
    *(short8_t*)dl = *(short8_t*)lo;
}

// One K-step for a wave's 2 M-tiles x 2 N-tiles, bf16x2-split (3 MFMA / tile).
__device__ __forceinline__ void gemm_step(
    f32x4 acc[2][2],
    const unsigned short* a0h, const unsigned short* a0l,
    const unsigned short* a1h, const unsigned short* a1l,
    const unsigned short* bh, const unsigned short* bl)
{
    short8_t Ah0 = *(const short8_t*)a0h;
    short8_t Al0 = *(const short8_t*)a0l;
    short8_t Ah1 = *(const short8_t*)a1h;
    short8_t Al1 = *(const short8_t*)a1l;
    short8_t Bh0 = *(const short8_t*)bh;
    short8_t Bl0 = *(const short8_t*)bl;
    short8_t Bh1 = *(const short8_t*)(bh + 512);
    short8_t Bl1 = *(const short8_t*)(bl + 512);
    acc[0][0] = MFMA16(Al0, Bh0, acc[0][0]);
    acc[0][0] = MFMA16(Ah0, Bl0, acc[0][0]);
    acc[0][0] = MFMA16(Ah0, Bh0, acc[0][0]);
    acc[0][1] = MFMA16(Al0, Bh1, acc[0][1]);
    acc[0][1] = MFMA16(Ah0, Bl1, acc[0][1]);
    acc[0][1] = MFMA16(Ah0, Bh1, acc[0][1]);
    acc[1][0] = MFMA16(Al1, Bh0, acc[1][0]);
    acc[1][0] = MFMA16(Ah1, Bl0, acc[1][0]);
    acc[1][0] = MFMA16(Ah1, Bh0, acc[1][0]);
    acc[1][1] = MFMA16(Al1, Bh1, acc[1][1]);
    acc[1][1] = MFMA16(Ah1, Bl1, acc[1][1]);
    acc[1][1] = MFMA16(Ah1, Bh1, acc[1][1]);
}

#define HNS 136   // s_hn row stride (128 + 8 pad) -> 272B rows, 16B aligned, conflict-free b128
#define NIS 40    // s_nin/s_efp row stride (32 + 8 pad) -> 80B rows
#define HES 132   // s_he f32 row stride

__global__ __launch_bounds__(256, 3) void gnn_mfma(
    const float* __restrict__ gf, const float* __restrict__ nf,
    const float* __restrict__ ef, const void* __restrict__ nmask_raw,
    const float* __restrict__ Wn, const float* __restrict__ bn,
    const float* __restrict__ We, const float* __restrict__ be,
    const float* __restrict__ Ws, const float* __restrict__ bs,
    const float* __restrict__ Wg, const float* __restrict__ bg,
    const float* __restrict__ Wc1, const float* __restrict__ bc1,
    const float* __restrict__ Wc2, const float* __restrict__ bc2,
    const unsigned short* __restrict__ wsp,
    float* __restrict__ out)
{
    const int b = blockIdx.x;
    const int t = threadIdx.x;

    __shared__ __align__(16) unsigned short s_hn_h[N_ + 1][HNS];
    __shared__ __align__(16) unsigned short s_hn_l[N_ + 1][HNS];
    __shared__ __align__(16) unsigned short s_nin_h[N_][NIS];
    __shared__ __align__(16) unsigned short s_nin_l[N_][NIS];
    __shared__ __align__(16) unsigned short s_efp_h[N_][NIS];
    __shared__ __align__(16) unsigned short s_efp_l[N_][NIS];
    __shared__ __align__(16) float s_he[N_][HES];
    __shared__ __align__(16) float s_g[GD_];
    __shared__ int   s_mi[N_];
    __shared__ float s_emask[N_];
    __shared__ __align__(16) float s_bias1[HN_];
    __shared__ __align__(16) float s_bias2[HE_];
    __shared__ float s_sc[N_];
    __shared__ float s_w[N_];
    __shared__ __align__(16) float s_tmp[256];
    __shared__ __align__(16) float s_aggf[HE_];
    __shared__ __align__(16) float s_hg[HG_];
    __shared__ __align__(16) float s_hc[HC_];

    // ---- node_mask dtype detection (bool-as-u8 vs int32), deterministic ----
    const unsigned char* mb = (const unsigned char*)nmask_raw;
    int cnt = __syncthreads_count(mb[t] != 0);
    const bool is_u8 = (cnt > 96);

    // ---- Phase A: loads + zero fills ----
    if (t < GD_) s_g[t] = gf[b * GD_ + t];
    for (int idx = t; idx < N_ * ND_; idx += 256) {   // node features -> hi/lo
        int n = idx >> 4, k = idx & 15;
        float v = nf[b * N_ * ND_ + idx];
        unsigned short h = f2bf(v);
        s_nin_h[n][k] = h;
        s_nin_l[n][k] = f2bf(v - bf2f(h));
    }
    for (int idx = t; idx < (N_ - 1) * ED_; idx += 256)   // raw ef -> temp (s_he)
        s_he[idx >> 3][idx & 7] = ef[b * (N_ - 1) * ED_ + idx];
    {   // zero: s_nin cols 32..39 (pad; never read but keep defined)
        int n = t >> 3, c = 32 + (t & 7);
        s_nin_h[n][c] = 0; s_nin_l[n][c] = 0;
    }
    if (t < 8) { s_nin_h[0][16 + t] = 0; s_nin_l[0][16 + t] = 0; }  // node0 edge_backward
    for (int idx = t; idx < N_ * 32; idx += 256) {  // s_efp cols 8..39 = 0 (NaN safety)
        int n = idx >> 5, c = 8 + (idx & 31);
        s_efp_h[n][c] = 0; s_efp_l[n][c] = 0;
    }
    if (t < HNS) { s_hn_h[N_][t] = 0; s_hn_l[N_][t] = 0; }          // h_node[32] = 0
    if (t < N_) {
        int mv = is_u8 ? (int)mb[b * N_ + t] : ((const int*)nmask_raw)[b * N_ + t];
        s_mi[t] = mv;
    }
    __syncthreads();

    // ---- Phase B: edge mask + combined biases (fold g @ W-tail) ----
    if (t < N_)
        s_emask[t] = (t < N_ - 1 && s_mi[t] != 0 && s_mi[t + 1] != 0) ? 1.0f : 0.0f;
    {
        int j = t & 127;
        if (t < 128) {
            float v = bn[j];
#pragma unroll
            for (int k = 0; k < GD_; ++k)
                v += s_g[k] * Wn[(ND_ + 2 * ED_ + k) * HN_ + j];
            s_bias1[j] = v;
        } else {
            float v = be[j];
#pragma unroll
            for (int k = 0; k < GD_; ++k)
                v += s_g[k] * We[(ED_ + 2 * HN_ + k) * HE_ + j];
            s_bias2[j] = v;
        }
    }
    __syncthreads();

    // ---- Phase C: split ef (raw -> s_efp, masked -> s_nin tail) ----
    {
        int e = t >> 3, k = t & 7;                 // e: 0..31
        float v = (e < N_ - 1) ? s_he[e][k] : 0.0f;
        unsigned short h = f2bf(v);
        s_efp_h[e][k] = h;
        s_efp_l[e][k] = f2bf(v - bf2f(h));
        float vm = v * s_emask[e];
        unsigned short hm = f2bf(vm);
        unsigned short lm = f2bf(vm - bf2f(hm));
        if (e < N_ - 1) {                          // edge_backward -> node e+1
            s_nin_h[e + 1][16 + k] = hm;
            s_nin_l[e + 1][16 + k] = lm;
        }
        s_nin_h[e][24 + k] = hm;                   // edge_forward -> node e (e=31: vm=0)
        s_nin_l[e][24 + k] = lm;
    }
    __syncthreads();

    const int w = t >> 6;          // wave 0..3 -> N-tiles {2w, 2w+1}
    const int l = t & 63;
    const int lrow = l & 15;       // A-fragment row / D col
    const int lk = (l >> 4) * 8;   // A-fragment k offset
    const int g4 = (l >> 4) * 4;   // D row base
    const int c0 = 32 * w + lrow;  // D col for nt=2w
    const int c1 = c0 + 16;        // D col for nt=2w+1

    // ---- Node MLP (MFMA): h_node = relu(nin @ Wn[0:32] + bias1) ----
    {
        f32x4 acc[2][2];
        float b0 = s_bias1[c0], b1 = s_bias1[c1];
        acc[0][0] = (f32x4){b0, b0, b0, b0};
        acc[1][0] = acc[0][0];
        acc[0][1] = (f32x4){b1, b1, b1, b1};
        acc[1][1] = acc[0][1];
        gemm_step(acc,
                  &s_nin_h[lrow][lk], &s_nin_l[lrow][lk],
                  &s_nin_h[16 + lrow][lk], &s_nin_l[16 + lrow][lk],
                  wsp + WNS_HI + ((2 * w) * 64 + l) * 8,
                  wsp + WNS_LO + ((2 * w) * 64 + l) * 8);
#pragma unroll
        for (int mt = 0; mt < 2; ++mt)
#pragma unroll
            for (int nt = 0; nt < 2; ++nt) {
                int col = nt ? c1 : c0;
#pragma unroll
                for (int r = 0; r < 4; ++r) {
                    int row = 16 * mt + g4 + r;
                    float v = fmaxf(acc[mt][nt][r], 0.0f);
                    unsigned short h = f2bf(v);
                    s_hn_h[row][col] = h;
                    s_hn_l[row][col] = f2bf(v - bf2f(h));
                }
            }
    }
    __syncthreads();

    // ---- Edge MLP (MFMA): 9 K-steps ----
    {
        f32x4 acc[2][2];
        float b0 = s_bias2[c0], b1 = s_bias2[c1];
        acc[0][0] = (f32x4){b0, b0, b0, b0};
        acc[1][0] = acc[0][0];
        acc[0][1] = (f32x4){b1, b1, b1, b1};
        acc[1][1] = acc[0][1];
        // step 0: raw edge features (K 0..7 real, rest zero both sides)
        gemm_step(acc,
                  &s_efp_h[lrow][lk], &s_efp_l[lrow][lk],
                  &s_efp_h[16 + lrow][lk], &s_efp_l[16 + lrow][lk],
                  wsp + WES_HI + (0 * 8 + 2 * w) * 64 * 8 + l * 8,
                  wsp + WES_LO + (0 * 8 + 2 * w) * 64 * 8 + l * 8);
        // steps 1..4: h_node[e]
#pragma unroll
        for (int s = 1; s <= 4; ++s) {
            int kb = (s - 1) * 32 + lk;
            gemm_step(acc,
                      &s_hn_h[lrow][kb], &s_hn_l[lrow][kb],
                      &s_hn_h[16 + lrow][kb], &s_hn_l[16 + lrow][kb],
                      wsp + WES_HI + (s * 8 + 2 * w) * 64 * 8 + l * 8,
                      wsp + WES_LO + (s * 8 + 2 * w) * 64 * 8 + l * 8);
        }
        // steps 5..8: h_node[e+1]  (row offset +1)
#pragma unroll
        for (int s = 5; s <= 8; ++s) {
            int kb = (s - 5) * 32 + lk;
            gemm_step(acc,
                      &s_hn_h[1 + lrow][kb], &s_hn_l[1 + lrow][kb],
                      &s_hn_h[17 + lrow][kb], &s_hn_l[17 + lrow][kb],
                      wsp + WES_HI + (s * 8 + 2 * w) * 64 * 8 + l * 8,
                      wsp + WES_LO + (s * 8 + 2 * w) * 64 * 8 + l * 8);
        }
#pragma unroll
        for (int mt = 0; mt < 2; ++mt)
#pragma unroll
            for (int nt = 0; nt < 2; ++nt) {
                int col = nt ? c1 : c0;
#pragma unroll
                for (int r = 0; r < 4; ++r)
                    s_he[16 * mt + g4 + r][col] = fmaxf(acc[mt][nt][r], 0.0f);
            }
    }
    __syncthreads();

    // ---- P3: scores + masked softmax ----
    {
        int c = t & 7, e = t >> 3;
        const float* he = &s_he[e][0];
        float p = 0.0f;
#pragma unroll
        for (int j0 = 0; j0 < 16; j0 += 4) {
            float4 h = *(const float4*)&he[c * 16 + j0];
            float4 wv = *(const float4*)&Ws[c * 16 + j0];
            p += h.x * wv.x + h.y * wv.y + h.z * wv.z + h.w * wv.w;
        }
        p += __shfl_xor(p, 1);
        p += __shfl_xor(p, 2);
        p += __shfl_xor(p, 4);
        if (c == 0) s_sc[e] = p + bs[0];
    }
    __syncthreads();
    if (t < 64) {
        float v = -INFINITY;
        if (t < N_ - 1)
            v = s_sc[t] * s_emask[t] + (1.0f - s_emask[t]) * (-1e9f);
        float m = v;
#pragma unroll
        for (int d = 32; d >= 1; d >>= 1) m = fmaxf(m, __shfl_xor(m, d));
        float e_ = (t < N_ - 1) ? expf(v - m) : 0.0f;
        float ssum = e_;
#pragma unroll
        for (int d = 32; d >= 1; d >>= 1) ssum += __shfl_xor(ssum, d);
        if (t < N_) s_w[t] = (t < N_ - 1) ? (e_ / ssum) : 0.0f;
    }
    __syncthreads();

    // ---- P4: weighted edge pooling ----
    {
        int j = t & 127, half = t >> 7;
        float p = 0.0f;
#pragma unroll
        for (int e = 0; e < 16; ++e) {
            int ee = half * 16 + e;
            p += s_he[ee][j] * s_w[ee];
        }
        s_tmp[half * 128 + j] = p;
    }
    __syncthreads();
    if (t < 128) s_aggf[t] = s_tmp[t] + s_tmp[128 + t];
    __syncthreads();

    // ---- P5: h_glob = relu(agg @ Wg + bg) ----
    {
        int j = t & 127, half = t >> 7;
        float p = 0.0f;
        for (int k = half * 64; k < half * 64 + 64; ++k)
            p += s_aggf[k] * Wg[k * HG_ + j];
        s_tmp[half * 128 + j] = p;
    }
    __syncthreads();
    if (t < 128) s_hg[t] = fmaxf(s_tmp[t] + s_tmp[128 + t] + bg[t], 0.0f);
    __syncthreads();

    // ---- P6: h_cls = relu(h_glob @ Wc1 + bc1) ----
    {
        int j = t & 63, q = t >> 6;
        float p = 0.0f;
        for (int k = q * 32; k < q * 32 + 32; ++k)
            p += s_hg[k] * Wc1[k * HC_ + j];
        s_tmp[q * 64 + j] = p;
    }
    __syncthreads();
    if (t < 64)
        s_hc[t] = fmaxf(s_tmp[t] + s_tmp[64 + t] + s_tmp[128 + t] + s_tmp[192 + t] + bc1[t], 0.0f);
    __syncthreads();

    // ---- P7: y = h_cls @ Wc2 + bc2 ----
    if (t < 64) {
        float p = s_hc[t] * Wc2[t];
#pragma unroll
        for (int d = 32; d >= 1; d >>= 1) p += __shfl_xor(p, d);
        if (t == 0) out[b] = p + bc2[0];
    }
}

// ======================= fallback: R1 f32 kernel =======================
__device__ __forceinline__ void tile_fma_4x4(
    float acc[4][4], const float* in0, const float* in1, const float* in2,
    const float* in3, int k, const float* __restrict__ W, int wrow, int c4)
{
    float in_[4][4];
    *(float4*)&in_[0][0] = *(const float4*)(in0 + k);
    *(float4*)&in_[1][0] = *(const float4*)(in1 + k);
    *(float4*)&in_[2][0] = *(const float4*)(in2 + k);
    *(float4*)&in_[3][0] = *(const float4*)(in3 + k);
#pragma unroll
    for (int kk = 0; kk < 4; ++kk) {
        float w_[4];
        *(float4*)w_ = *(const float4*)&W[(wrow + kk) * 128 + c4];
#pragma unroll
        for (int r = 0; r < 4; ++r)
#pragma unroll
            for (int c = 0; c < 4; ++c)
                acc[r][c] += in_[r][kk] * w_[c];
    }
}

__global__ __launch_bounds__(256, 3) void gnn_fused(
    const float* __restrict__ gf, const float* __restrict__ nf,
    const float* __restrict__ ef, const void* __restrict__ nmask_raw,
    const float* __restrict__ Wn, const float* __restrict__ bn,
    const float* __restrict__ We, const float* __restrict__ be,
    const float* __restrict__ Ws, const float* __restrict__ bs,
    const float* __restrict__ Wg, const float* __restrict__ bg,
    const float* __restrict__ Wc1, const float* __restrict__ bc1,
    const float* __restrict__ Wc2, const float* __restrict__ bc2,
    float* __restrict__ out)
{
    const int b = blockIdx.x;
    const int t = threadIdx.x;

    __shared__ __align__(16) float s_g[GD_];
    __shared__ int   s_mi[N_];
    __shared__ float s_emask[N_];
    __shared__ __align__(16) float s_ef[N_][ED_];
    __shared__ __align__(16) float s_efm[N_][ED_];
    __shared__ __align__(16) float s_nin[N_][32];
    __shared__ __align__(16) float s_hn[N_ + 1][HN_];
    __shared__ __align__(16) float s_he[N_][HE_];
    __shared__ __align__(16) float s_bias1[HN_];
    __shared__ __align__(16) float s_bias2[HE_];
    __shared__ float s_sc[N_];
    __shared__ float s_w[N_];
    __shared__ __align__(16) float s_tmp[256];
    __shared__ __align__(16) float s_aggf[HE_];
    __shared__ __align__(16) float s_hg[HG_];
    __shared__ __align__(16) float s_hc[HC_];

    const unsigned char* mb = (const unsigned char*)nmask_raw;
    int cnt = __syncthreads_count(mb[t] != 0);
    const bool is_u8 = (cnt > 96);

    if (t < GD_) s_g[t] = gf[b * GD_ + t];
    for (int idx = t; idx < N_ * ND_; idx += 256)
        s_nin[idx >> 4][idx & 15] = nf[b * N_ * ND_ + idx];
    for (int idx = t; idx < (N_ - 1) * ED_; idx += 256)
        s_ef[idx >> 3][idx & 7] = ef[b * (N_ - 1) * ED_ + idx];
    if (t < ED_) s_ef[N_ - 1][t] = 0.0f;
    if (t < HN_) s_hn[N_][t] = 0.0f;
    if (t < N_) {
        int mv = is_u8 ? (int)mb[b * N_ + t] : ((const int*)nmask_raw)[b * N_ + t];
        s_mi[t] = mv;
    }
    __syncthreads();

    if (t < N_)
        s_emask[t] = (t < N_ - 1 && s_mi[t] != 0 && s_mi[t + 1] != 0) ? 1.0f : 0.0f;
    __syncthreads();

    {
        int e = t >> 3, k = t & 7;
        s_efm[e][k] = s_ef[e][k] * s_emask[e];
    }
    {
        int j = t & 127;
        if (t < 128) {
            float v = bn[j];
#pragma unroll
            for (int k = 0; k < GD_; ++k)
                v += s_g[k] * Wn[(ND_ + 2 * ED_ + k) * HN_ + j];
            s_bias1[j] = v;
        } else {
            float v = be[j];
#pragma unroll
            for (int k = 0; k < GD_; ++k)
                v += s_g[k] * We[(ED_ + 2 * HN_ + k) * HE_ + j];
            s_bias2[j] = v;
        }
    }
    __syncthreads();

    for (int idx = t; idx < N_ * 16; idx += 256) {
        int n = idx >> 4, kk = idx & 15;
        if (kk < 8) s_nin[n][16 + kk]       = (n > 0)       ? s_efm[n - 1][kk] : 0.0f;
        else        s_nin[n][24 + (kk - 8)] = (n < N_ - 1)  ? s_efm[n][kk - 8] : 0.0f;
    }
    __syncthreads();

    const int jg = t & 31, rg = t >> 5;
    const int c4 = jg * 4, r4 = rg * 4;

    {
        float acc[4][4];
#pragma unroll
        for (int r = 0; r < 4; ++r)
#pragma unroll
            for (int c = 0; c < 4; ++c) acc[r][c] = s_bias1[c4 + c];
        const float* i0 = &s_nin[r4 + 0][0];
        const float* i1 = &s_nin[r4 + 1][0];
        const float* i2 = &s_nin[r4 + 2][0];
        const float* i3 = &s_nin[r4 + 3][0];
#pragma unroll
        for (int k = 0; k < 32; k += 4)
            tile_fma_4x4(acc, i0, i1, i2, i3, k, Wn, k, c4);
#pragma unroll
        for (int r = 0; r < 4; ++r)
#pragma unroll
            for (int c = 0; c < 4; ++c)
                s_hn[r4 + r][c4 + c] = fmaxf(acc[r][c], 0.0f);
    }
    __syncthreads();

    {
        float acc[4][4];
#pragma unroll
        for (int r = 0; r < 4; ++r)
#pragma unroll
            for (int c = 0; c < 4; ++c) acc[r][c] = s_bias2[c4 + c];
        {
            const float* i0 = &s_ef[r4 + 0][0];
            const float* i1 = &s_ef[r4 + 1][0];
            const float* i2 = &s_ef[r4 + 2][0];
            const float* i3 = &s_ef[r4 + 3][0];
#pragma unroll
            for (int k = 0; k < 8; k += 4)
                tile_fma_4x4(acc, i0, i1, i2, i3, k, We, k, c4);
        }
        {
            const float* i0 = &s_hn[r4 + 0][0];
            const float* i1 = &s_hn[r4 + 1][0];
            const float* i2 = &s_hn[r4 + 2][0];
            const float* i3 = &s_hn[r4 + 3][0];
#pragma unroll 4
            for (int k = 0; k < 128; k += 4)
                tile_fma_4x4(acc, i0, i1, i2, i3, k, We, 8 + k, c4);
        }
        {
            const float* i0 = &s_hn[r4 + 1][0];
            const float* i1 = &s_hn[r4 + 2][0];
            const float* i2 = &s_hn[r4 + 3][0];
            const float* i3 = &s_hn[r4 + 4][0];
#pragma unroll 4
            for (int k = 0; k < 128; k += 4)
                tile_fma_4x4(acc, i0, i1, i2, i3, k, We, 136 + k, c4);
        }
#pragma unroll
        for (int r = 0; r < 4; ++r)
#pragma unroll
            for (int c = 0; c < 4; ++c)
                s_he[r4 + r][c4 + c] = fmaxf(acc[r][c], 0.0f);
    }
    __syncthreads();

    {
        int c = t & 7, e = t >> 3;
        const float* he = &s_he[e][0];
        float p = 0.0f;
#pragma unroll
        for (int j0 = 0; j0 < 16; j0 += 4) {
            float4 h = *(const float4*)&he[c * 16 + j0];
            float4 wv = *(const float4*)&Ws[c * 16 + j0];
            p += h.x * wv.x + h.y * wv.y + h.z * wv.z + h.w * wv.w;
        }
        p += __shfl_xor(p, 1);
        p += __shfl_xor(p, 2);
        p += __shfl_xor(p, 4);
        if (c == 0) s_sc[e] = p + bs[0];
    }
    __syncthreads();
    if (t < 64) {
        float v = -INFINITY;
        if (t < N_ - 1)
            v = s_sc[t] * s_emask[t] + (1.0f - s_emask[t]) * (-1e9f);
        float m = v;
#pragma unroll
        for (int d = 32; d >= 1; d >>= 1) m = fmaxf(m, __shfl_xor(m, d));
        float e_ = (t < N_ - 1) ? expf(v - m) : 0.0f;
        float ssum = e_;
#pragma unroll
        for (int d = 32; d >= 1; d >>= 1) ssum += __shfl_xor(ssum, d);
        if (t < N_) s_w[t] = (t < N_ - 1) ? (e_ / ssum) : 0.0f;
    }
    __syncthreads();

    {
        int j = t & 127, half = t >> 7;
        float p = 0.0f;
#pragma unroll
        for (int e = 0; e < 16; ++e) {
            int ee = half * 16 + e;
            p += s_he[ee][j] * s_w[ee];
        }
        s_tmp[half * 128 + j] = p;
    }
    __syncthreads();
    if (t < 128) s_aggf[t] = s_tmp[t] + s_tmp[128 + t];
    __syncthreads();

    {
        int j = t & 127, half = t >> 7;
        float p = 0.0f;
        for (int k = half * 64; k < half * 64 + 64; ++k)
            p += s_aggf[k] * Wg[k * HG_ + j];
        s_tmp[half * 128 + j] = p;
    }
    __syncthreads();
    if (t < 128) s_hg[t] = fmaxf(s_tmp[t] + s_tmp[128 + t] + bg[t], 0.0f);
    __syncthreads();

    {
        int j = t & 63, q = t >> 6;
        float p = 0.0f;
        for (int k = q * 32; k < q * 32 + 32; ++k)
            p += s_hg[k] * Wc1[k * HC_ + j];
        s_tmp[q * 64 + j] = p;
    }
    __syncthreads();
    if (t < 64)
        s_hc[t] = fmaxf(s_tmp[t] + s_tmp[64 + t] + s_tmp[128 + t] + s_tmp[192 + t] + bc1[t], 0.0f);
    __syncthreads();

    if (t < 64) {
        float p = s_hc[t] * Wc2[t];
#pragma unroll
        for (int d = 32; d >= 1; d >>= 1) p += __shfl_xor(p, d);
        if (t == 0) out[b] = p + bc2[0];
    }
}

extern "C" void kernel_launch(void* const* d_in, const int* in_sizes, int n_in,
                              void* d_out, int out_size, void* d_ws, size_t ws_size,
                              hipStream_t stream) {
    const float* gf  = (const float*)d_in[0];
    const float* nf  = (const float*)d_in[1];
    const float* ef  = (const float*)d_in[2];
    const void*  nm  = d_in[3];
    const float* Wn  = (const float*)d_in[4];
    const float* bn  = (const float*)d_in[5];
    const float* We  = (const float*)d_in[6];
    const float* be  = (const float*)d_in[7];
    const float* Ws  = (const float*)d_in[8];
    const float* bs  = (const float*)d_in[9];
    const float* Wg  = (const float*)d_in[10];
    const float* bg  = (const float*)d_in[11];
    const float* Wc1 = (const float*)d_in[12];
    const float* bc1 = (const float*)d_in[13];
    const float* Wc2 = (const float*)d_in[14];
    const float* bc2 = (const float*)d_in[15];
    float* out = (float*)d_out;

    const int B = in_sizes[0] / GD_;

    if (ws_size >= (size_t)WS_BYTES) {
        prep_weights<<<20, 256, 0, stream>>>(Wn, We, (unsigned short*)d_ws);
        gnn_mfma<<<B, 256, 0, stream>>>(gf, nf, ef, nm, Wn, bn, We, be, Ws, bs,
                                        Wg, bg, Wc1, bc1, Wc2, bc2,
                                        (const unsigned short*)d_ws, out);
    } else {
        gnn_fused<<<B, 256, 0, stream>>>(gf, nf, ef, nm, Wn, bn, We, be, Ws, bs,
                                         Wg, bg, Wc1, bc1, Wc2, bc2, out);
    }
}